// Round 1
// baseline (291.608 us; speedup 1.0000x reference)
//
#include <hip/hip_runtime.h>

#define NN 50000
#define EE 800000
#define ET (EE + NN)
#define NCH ((NN + 255) / 256)                       // 196 scan chunks
#define DEGB ((ET + 255) / 256)                      // 3322 degree/fill blocks
#define WPB ((128 * 128 + 128 * 64 + 255) / 256)     // 96 wtprep blocks
#define GEMB ((NN + 63) / 64)                        // 782 gemm blocks

typedef unsigned short ushort_t;
using bf16x8 = __attribute__((ext_vector_type(8))) short;
using f32x4  = __attribute__((ext_vector_type(4))) float;

__device__ __forceinline__ float bf2f(ushort_t u) {
    return __uint_as_float(((unsigned int)u) << 16);
}
__device__ __forceinline__ ushort_t f2bf(float f) {
    unsigned int u = __float_as_uint(f);
    u += 0x7fffu + ((u >> 16) & 1u);
    return (ushort_t)(u >> 16);
}
__device__ __forceinline__ float lrelu(float e) {
    return fmaxf(e, 0.f) + 0.2f * fminf(e, 0.f);
}
__device__ __forceinline__ float ldf(const void* p, int i, bool f32) {
    return f32 ? ((const float*)p)[i] : bf2f(((const ushort_t*)p)[i]);
}

// ---- block-local dtype sniffers (per-wave ballot; replaces the serial sniff kernel) ----
// fp32 test: same heuristic as before (75% of sampled words look like plausible floats)
__device__ __forceinline__ bool sniff_f32(const unsigned int* __restrict__ xw) {
    int lane = threadIdx.x & 63;
    float v = __uint_as_float(xw[lane]);
    float a = fabsf(v);
    bool ok = (a > 1e-6f && a < 1e6f) || v == 0.f;
    unsigned long long m = __ballot(ok);
    return __popcll(m) >= 48;
}
// int64 test: odd words are int64 high halves == 0 (values < 2^31); int32 data is random src ids
__device__ __forceinline__ bool sniff_i64(const int* __restrict__ eiw) {
    int lane = threadIdx.x & 63;
    unsigned long long m = __ballot(eiw[2 * lane + 1] != 0);
    return __popcll(m) <= 4;
}

__device__ __forceinline__ void edge_sd(const int* ei, int i, bool i64, int& s, int& d) {
    if (i < EE) {
        if (i64) { s = ei[2 * i]; d = ei[2 * (EE + i)]; }
        else     { s = ei[i];     d = ei[EE + i]; }
    } else {
        s = d = i - EE;
    }
}
__device__ __forceinline__ int edge_d(const int* ei, int i, bool i64) {
    if (i < EE) return i64 ? ei[2 * (EE + i)] : ei[EE + i];
    return i - EE;
}

// ---------------- L1: degree histogram (8 XCD-local slices) + W pre-transpose, fused by block range ----------------
__global__ __launch_bounds__(256) void prep_kernel(const int* __restrict__ ei, int* __restrict__ deg8,
                                                   const unsigned int* __restrict__ xw,
                                                   const void* W1v, const void* W2v,
                                                   ushort_t* __restrict__ Wt1, ushort_t* __restrict__ Wt2) {
    int b = blockIdx.x;
    if (b < DEGB) {
        bool i64 = sniff_i64(ei);
        int i = b * 256 + threadIdx.x;
        if (i >= ET) return;
        int g = b & 7;                        // blockIdx->XCD round-robin: keep atomic lines in one L2
        int d = edge_d(ei, i, i64);
        atomicAdd(&deg8[(size_t)g * NN + d], 1);
    } else {
        bool f32 = sniff_f32(xw);
        int i = (b - DEGB) * 256 + threadIdx.x;
        if (i < 128 * 128) {                  // W1[k][nc] -> Wt1[nc][k]
            int k = i >> 7, nc = i & 127;
            ushort_t v = f32 ? f2bf(((const float*)W1v)[i]) : ((const ushort_t*)W1v)[i];
            Wt1[nc * 128 + k] = v;
        }
        int j = i - 128 * 128;
        if (j >= 0 && j < 128 * 64) {         // W2[k][nc] -> Wt2[nc][k]
            int k = j >> 6, nc = j & 63;
            ushort_t v = f32 ? f2bf(((const float*)W2v)[j]) : ((const ushort_t*)W2v)[j];
            Wt2[nc * 128 + k] = v;
        }
    }
}

// ---------------- decoupled-lookback scan over 196 chunks (replaces scanA/B/C) ----------------
// Single-word protocol: state[b] = flag(63:62) | value(31:0). 0=not ready, 1=aggregate, 2=inclusive prefix.
// Safe: 196 scan blocks occupy the lowest blockIdx range; all co-resident on 256 CUs.
#define FLG_A (1ull << 62)
#define FLG_P (2ull << 62)

__device__ void scan_body(int b, int* __restrict__ deg8, int* __restrict__ rowptr,
                          unsigned long long* __restrict__ state) {
    __shared__ int wsum[4];
    __shared__ int bpref;
    int t = threadIdx.x;
    int node = b * 256 + t;
    int lane = t & 63, wid = t >> 6;
    int dv[8];
    int v = 0;
    if (node < NN) {
        #pragma unroll
        for (int g = 0; g < 8; ++g) {
            dv[g] = deg8[(size_t)g * NN + node];
            v += dv[g];
        }
    }
    int x = v;
    #pragma unroll
    for (int off = 1; off < 64; off <<= 1) {
        int y = __shfl_up(x, off);
        if (lane >= off) x += y;
    }
    if (lane == 63) wsum[wid] = x;
    __syncthreads();
    if (t < 4) {
        int s = wsum[t];
        #pragma unroll
        for (int off = 1; off < 4; off <<= 1) {
            int y = __shfl_up(s, off);
            if (t >= off) s += y;
        }
        wsum[t] = s;
    }
    __syncthreads();
    int total = wsum[3];                      // block aggregate
    if (t == 0) {
        int prefix = 0;
        if (b == 0) {
            atomicExch(&state[0], FLG_P | (unsigned long long)(unsigned)total);
        } else {
            atomicExch(&state[b], FLG_A | (unsigned long long)(unsigned)total);
            int j = b - 1;
            while (true) {
                unsigned long long sv = atomicAdd(&state[j], 0ull);  // device-coherent read
                unsigned long long f = sv >> 62;
                if (f == 0) { __builtin_amdgcn_s_sleep(2); continue; }
                prefix += (int)(unsigned)(sv & 0xffffffffull);
                if (f == 2) break;
                --j;
            }
            atomicExch(&state[b], FLG_P | (unsigned long long)(unsigned)(prefix + total));
        }
        bpref = prefix;
    }
    __syncthreads();
    int excl = x - v + ((wid > 0) ? wsum[wid - 1] : 0);
    if (node < NN) {
        int run = bpref + excl;
        rowptr[node] = run;
        #pragma unroll
        for (int g = 0; g < 8; ++g) {         // deg8 becomes per-slice write cursors for fill
            deg8[(size_t)g * NN + node] = run;
            run += dv[g];
        }
    }
    if (b == NCH - 1 && t == 255) rowptr[NN] = bpref + total;
}

// ---------------- MFMA GEMM body (A streamed global->VGPR, B (Wt) L2-resident) ----------------
template <bool AEXT, int NCOL, int NH>
__device__ __forceinline__ void mgemm_body(int bid, const void* Av, const ushort_t* __restrict__ Wt,
                                           const void* a_src, const void* a_dst,
                                           ushort_t* __restrict__ outb, float* __restrict__ asrc,
                                           float* __restrict__ adst, int n, bool f32) {
    constexpr int K = 128;
    constexpr int NCT = NCOL / 16;
    bool af32 = AEXT && f32;                  // internal A (hmid) is always bf16
    int t = threadIdx.x;
    int lane = t & 63, wid = t >> 6;
    int m = lane & 15, quad = lane >> 4;
    int rbase = bid * 64 + wid * 16;
    int row = rbase + m;
    bool rok = row < n;

    bf16x8 af[4];
    if (rok) {
        if (!af32) {
            const ushort_t* ap = (const ushort_t*)Av + (size_t)row * K + quad * 8;
            #pragma unroll
            for (int kk = 0; kk < 4; ++kk) af[kk] = *(const bf16x8*)(ap + kk * 32);
        } else {
            const float* ap = (const float*)Av + (size_t)row * K + quad * 8;
            #pragma unroll
            for (int kk = 0; kk < 4; ++kk) {
                float4 q0 = *(const float4*)(ap + kk * 32);
                float4 q1 = *(const float4*)(ap + kk * 32 + 4);
                bf16x8 v;
                v[0] = (short)f2bf(q0.x); v[1] = (short)f2bf(q0.y);
                v[2] = (short)f2bf(q0.z); v[3] = (short)f2bf(q0.w);
                v[4] = (short)f2bf(q1.x); v[5] = (short)f2bf(q1.y);
                v[6] = (short)f2bf(q1.z); v[7] = (short)f2bf(q1.w);
                af[kk] = v;
            }
        }
    } else {
        #pragma unroll
        for (int kk = 0; kk < 4; ++kk) af[kk] = (bf16x8){0, 0, 0, 0, 0, 0, 0, 0};
    }

    f32x4 acc[NCT];
    #pragma unroll
    for (int c = 0; c < NCT; ++c) acc[c] = (f32x4){0.f, 0.f, 0.f, 0.f};

    const ushort_t* wp = Wt + (size_t)m * K + quad * 8;
    #pragma unroll
    for (int c = 0; c < NCT; ++c) {
        const ushort_t* wc = wp + (size_t)c * 16 * K;
        #pragma unroll
        for (int kk = 0; kk < 4; ++kk) {
            bf16x8 bf = *(const bf16x8*)(wc + kk * 32);
            acc[c] = __builtin_amdgcn_mfma_f32_16x16x32_bf16(af[kk], bf, acc[c], 0, 0, 0);
        }
    }

    int orow0 = rbase + quad * 4;
    #pragma unroll
    for (int c = 0; c < NCT; ++c) {
        #pragma unroll
        for (int r = 0; r < 4; ++r) {
            int orow = orow0 + r;
            if (orow < n) outb[(size_t)orow * NCOL + c * 16 + m] = f2bf(acc[c][r]);
        }
    }

    if (NH == 8) {
        #pragma unroll
        for (int c = 0; c < NCT; ++c) {
            float as = ldf(a_src, c * 16 + m, f32);
            float ad = ldf(a_dst, c * 16 + m, f32);
            float ps[4], pd[4];
            #pragma unroll
            for (int r = 0; r < 4; ++r) { ps[r] = acc[c][r] * as; pd[r] = acc[c][r] * ad; }
            #pragma unroll
            for (int stp = 1; stp < 16; stp <<= 1) {
                #pragma unroll
                for (int r = 0; r < 4; ++r) {
                    ps[r] += __shfl_xor(ps[r], stp);
                    pd[r] += __shfl_xor(pd[r], stp);
                }
            }
            if (m == 0) {
                #pragma unroll
                for (int r = 0; r < 4; ++r) {
                    int orow = orow0 + r;
                    if (orow < n) {
                        asrc[(size_t)orow * 8 + c] = ps[r];
                        adst[(size_t)orow * 8 + c] = pd[r];
                    }
                }
            }
        }
    } else {
        float ps[4] = {0.f, 0.f, 0.f, 0.f}, pd[4] = {0.f, 0.f, 0.f, 0.f};
        #pragma unroll
        for (int c = 0; c < NCT; ++c) {
            float as = ldf(a_src, c * 16 + m, f32);
            float ad = ldf(a_dst, c * 16 + m, f32);
            #pragma unroll
            for (int r = 0; r < 4; ++r) {
                ps[r] = fmaf(acc[c][r], as, ps[r]);
                pd[r] = fmaf(acc[c][r], ad, pd[r]);
            }
        }
        #pragma unroll
        for (int stp = 1; stp < 16; stp <<= 1) {
            #pragma unroll
            for (int r = 0; r < 4; ++r) {
                ps[r] += __shfl_xor(ps[r], stp);
                pd[r] += __shfl_xor(pd[r], stp);
            }
        }
        if (m == 0) {
            #pragma unroll
            for (int r = 0; r < 4; ++r) {
                int orow = orow0 + r;
                if (orow < n) { asrc[orow] = ps[r]; adst[orow] = pd[r]; }
            }
        }
    }
}

// ---------------- L2: lookback scan (blocks 0..195, dispatched first) + layer-1 GEMM, fused ----------------
__global__ __launch_bounds__(256) void scan_mgemm1_kernel(int* __restrict__ deg8, int* __restrict__ rowptr,
                                                          unsigned long long* __restrict__ state,
                                                          const void* xv, const ushort_t* __restrict__ Wt1,
                                                          const void* as1, const void* ad1,
                                                          ushort_t* __restrict__ h1b,
                                                          float* __restrict__ asrc1, float* __restrict__ adst1) {
    if (blockIdx.x < NCH) {
        scan_body(blockIdx.x, deg8, rowptr, state);
        return;
    }
    bool f32 = sniff_f32((const unsigned int*)xv);
    mgemm_body<true, 128, 8>(blockIdx.x - NCH, xv, Wt1, as1, ad1, h1b, asrc1, adst1, NN, f32);
}

__global__ __launch_bounds__(256) void mgemm2_kernel(const void* Av, const ushort_t* __restrict__ Wt,
                                                     const void* a_src, const void* a_dst,
                                                     ushort_t* __restrict__ outb, float* __restrict__ asrc,
                                                     float* __restrict__ adst, const unsigned int* __restrict__ xw) {
    bool f32 = sniff_f32(xw);
    mgemm_body<false, 64, 1>(blockIdx.x, Av, Wt, a_src, a_dst, outb, asrc, adst, NN, f32);
}

// ---------------- L3: CSR fill via atomic cursors (no rank array, single ei re-read) ----------------
__global__ __launch_bounds__(256) void fill_kernel(const int* __restrict__ ei, int* __restrict__ deg8,
                                                   int* __restrict__ col) {
    bool i64 = sniff_i64(ei);
    int i = blockIdx.x * 256 + threadIdx.x;
    if (i >= ET) return;
    int g = blockIdx.x & 7;                   // same blockIdx->g map as the degree pass
    int s, d;
    edge_sd(ei, i, i64, s, d);
    int pos = atomicAdd(&deg8[(size_t)g * NN + d], 1);
    col[pos] = s;
}

// ---------------- layer-1 aggregation: one wave per dst node, two-phase pipelined gather ----------------
__global__ __launch_bounds__(256) void agg1_kernel(const unsigned int* __restrict__ xw,
                                                   const int* __restrict__ rowptr, const int* __restrict__ col,
                                                   const ushort_t* __restrict__ h1b,
                                                   const float* __restrict__ asrc, const float* __restrict__ adst,
                                                   const void* b1, ushort_t* __restrict__ hmidb) {
    __shared__ float wle[4][8 * 72];
    __shared__ int loff[4][64];
    bool f32 = sniff_f32(xw);
    int lane = threadIdx.x & 63, wid = threadIdx.x >> 6;
    int d = blockIdx.x * 4 + wid;
    if (d >= NN) return;                 // per-wave LDS only; no __syncthreads in this kernel
    int start = rowptr[d], end = rowptr[d + 1];
    int hB = lane >> 3;
    const float4* dp = (const float4*)(adst + (size_t)d * 8);
    float4 ad0 = dp[0], ad1 = dp[1];
    const char* hb = (const char*)h1b + lane * 4;
    float acc0 = 0.f, acc1 = 0.f, ssum = 0.f;
    for (int chunk = start; chunk < end; chunk += 64) {
        int cnt = min(64, end - chunk);
        int c = (chunk + lane < end) ? col[chunk + lane] : 0;
        loff[wid][lane] = c << 8;
        if (lane < cnt) {
            const float4* ap = (const float4*)(asrc + (size_t)c * 8);
            float4 s0 = ap[0], s1 = ap[1];
            wle[wid][0 * 72 + lane] = __expf(lrelu(s0.x + ad0.x));
            wle[wid][1 * 72 + lane] = __expf(lrelu(s0.y + ad0.y));
            wle[wid][2 * 72 + lane] = __expf(lrelu(s0.z + ad0.z));
            wle[wid][3 * 72 + lane] = __expf(lrelu(s0.w + ad0.w));
            wle[wid][4 * 72 + lane] = __expf(lrelu(s1.x + ad1.x));
            wle[wid][5 * 72 + lane] = __expf(lrelu(s1.y + ad1.y));
            wle[wid][6 * 72 + lane] = __expf(lrelu(s1.z + ad1.z));
            wle[wid][7 * 72 + lane] = __expf(lrelu(s1.w + ad1.w));
        }
        #pragma unroll 4
        for (int j = 0; j < cnt; ++j) {
            int off = loff[wid][j];
            float ex = wle[wid][hB * 72 + j];
            unsigned int hv = *(const unsigned int*)(hb + off);
            ssum += ex;
            acc0 = fmaf(ex, __uint_as_float(hv << 16), acc0);
            acc1 = fmaf(ex, __uint_as_float(hv & 0xffff0000u), acc1);
        }
    }
    float inv = 1.f / (ssum + 1e-16f);
    float o0 = fmaf(acc0, inv, ldf(b1, lane * 2, f32));
    float o1 = fmaf(acc1, inv, ldf(b1, lane * 2 + 1, f32));
    o0 = (o0 > 0.f) ? o0 : (__expf(o0) - 1.f);   // ELU
    o1 = (o1 > 0.f) ? o1 : (__expf(o1) - 1.f);
    unsigned int pk = ((unsigned int)f2bf(o1) << 16) | (unsigned int)f2bf(o0);
    *(unsigned int*)(hmidb + (size_t)d * 128 + lane * 2) = pk;
}

// ---------------- layer-2 aggregation + log_softmax ----------------
__global__ __launch_bounds__(256) void agg2_kernel(const unsigned int* __restrict__ xw,
                                                   const int* __restrict__ rowptr, const int* __restrict__ col,
                                                   const ushort_t* __restrict__ h2b,
                                                   const float* __restrict__ asrc, const float* __restrict__ adst,
                                                   const void* b2, float* __restrict__ out) {
    __shared__ float wle[4][64];
    __shared__ int loff[4][64];
    bool f32 = sniff_f32(xw);
    int lane = threadIdx.x & 63, wid = threadIdx.x >> 6;
    int d = blockIdx.x * 4 + wid;
    if (d >= NN) return;
    int start = rowptr[d], end = rowptr[d + 1];
    float ad = adst[d];
    const char* hb = (const char*)h2b + lane * 2;
    float acc = 0.f, ssum = 0.f;
    for (int chunk = start; chunk < end; chunk += 64) {
        int cnt = min(64, end - chunk);
        int c = (chunk + lane < end) ? col[chunk + lane] : 0;
        loff[wid][lane] = c << 7;
        if (lane < cnt) wle[wid][lane] = __expf(lrelu(asrc[c] + ad));
        #pragma unroll 4
        for (int j = 0; j < cnt; ++j) {
            int off = loff[wid][j];
            float ex = wle[wid][j];
            float hv = bf2f(*(const ushort_t*)(hb + off));
            ssum += ex;
            acc = fmaf(ex, hv, acc);
        }
    }
    float o = acc / (ssum + 1e-16f) + ldf(b2, lane, f32);
    float mm = o;
    #pragma unroll
    for (int off = 1; off < 64; off <<= 1) mm = fmaxf(mm, __shfl_xor(mm, off));
    float texp = __expf(o - mm);
    float ts = texp;
    #pragma unroll
    for (int off = 1; off < 64; off <<= 1) ts += __shfl_xor(ts, off);
    float ls = o - mm - __logf(ts);
    out[(size_t)d * 64 + lane] = o;
    out[(size_t)NN * 64 + (size_t)d * 64 + lane] = ls;
}

extern "C" void kernel_launch(void* const* d_in, const int* in_sizes, int n_in,
                              void* d_out, int out_size, void* d_ws, size_t ws_size,
                              hipStream_t stream) {
    const void* x   = d_in[0];
    const int*  ei  = (const int*)d_in[1];
    const void* W1  = d_in[2];
    const void* as1 = d_in[3];
    const void* ad1 = d_in[4];
    const void* b1  = d_in[5];
    const void* W2  = d_in[6];
    const void* as2 = d_in[7];
    const void* ad2 = d_in[8];
    const void* b2  = d_in[9];
    float* out = (float*)d_out;

    char* w = (char*)d_ws;
    auto alloc = [&](size_t bytes) {
        void* p = (void*)w;
        w += (bytes + 255) & ~(size_t)255;
        return p;
    };
    int* deg8     = (int*)alloc((size_t)8 * NN * 4 + 4096);   // +state tail
    unsigned long long* state = (unsigned long long*)((char*)deg8 + (size_t)8 * NN * 4);
    int* rowptr   = (int*)alloc((size_t)(NN + 1) * 4);
    int* colx     = (int*)alloc((size_t)ET * 4);
    ushort_t* Wt1 = (ushort_t*)alloc((size_t)128 * 128 * 2);
    ushort_t* Wt2 = (ushort_t*)alloc((size_t)64 * 128 * 2);
    ushort_t* h1b = (ushort_t*)alloc((size_t)NN * 128 * 2);
    float* asrc1  = (float*)alloc((size_t)NN * 8 * 4);
    float* adst1  = (float*)alloc((size_t)NN * 8 * 4);
    ushort_t* hmidb = (ushort_t*)alloc((size_t)NN * 128 * 2);
    ushort_t* h2b = (ushort_t*)alloc((size_t)NN * 64 * 2);
    float* asrc2  = (float*)alloc((size_t)NN * 4);
    float* adst2  = (float*)alloc((size_t)NN * 4);

    hipMemsetAsync(deg8, 0, (size_t)8 * NN * 4 + (size_t)NCH * 8, stream);

    prep_kernel<<<DEGB + WPB, 256, 0, stream>>>(ei, deg8, (const unsigned int*)x, W1, W2, Wt1, Wt2);
    scan_mgemm1_kernel<<<NCH + GEMB, 256, 0, stream>>>(deg8, rowptr, state, x, Wt1, as1, ad1,
                                                       h1b, asrc1, adst1);
    fill_kernel<<<DEGB, 256, 0, stream>>>(ei, deg8, colx);
    agg1_kernel<<<(NN + 3) / 4, 256, 0, stream>>>((const unsigned int*)x, rowptr, colx, h1b,
                                                  asrc1, adst1, b1, hmidb);
    mgemm2_kernel<<<GEMB, 256, 0, stream>>>((const void*)hmidb, Wt2, as2, ad2, h2b, asrc2, adst2,
                                            (const unsigned int*)x);
    agg2_kernel<<<(NN + 3) / 4, 256, 0, stream>>>((const unsigned int*)x, rowptr, colx, h2b,
                                                  asrc2, adst2, b2, out);
}

// Round 2
// 253.429 us; speedup vs baseline: 1.1506x; 1.1506x over previous
//
#include <hip/hip_runtime.h>

#define NN 50000
#define EE 800000
#define ET (EE + NN)
#define NCH ((NN + 255) / 256)                       // 196 scan chunks
#define DEGB ((ET + 255) / 256)                      // 3322 degree/fill blocks
#define WPB ((128 * 128 + 128 * 64 + 255) / 256)     // 96 wtprep blocks
#define GEMB ((NN + 63) / 64)                        // 782 gemm blocks

typedef unsigned short ushort_t;
using bf16x8 = __attribute__((ext_vector_type(8))) short;
using f32x4  = __attribute__((ext_vector_type(4))) float;

__device__ __forceinline__ float bf2f(ushort_t u) {
    return __uint_as_float(((unsigned int)u) << 16);
}
__device__ __forceinline__ ushort_t f2bf(float f) {
    unsigned int u = __float_as_uint(f);
    u += 0x7fffu + ((u >> 16) & 1u);
    return (ushort_t)(u >> 16);
}
__device__ __forceinline__ float lrelu(float e) {
    return fmaxf(e, 0.f) + 0.2f * fminf(e, 0.f);
}
__device__ __forceinline__ float ldf(const void* p, int i, bool f32) {
    return f32 ? ((const float*)p)[i] : bf2f(((const ushort_t*)p)[i]);
}

// ---- block-local dtype sniffers (per-wave ballot) ----
__device__ __forceinline__ bool sniff_f32(const unsigned int* __restrict__ xw) {
    int lane = threadIdx.x & 63;
    float v = __uint_as_float(xw[lane]);
    float a = fabsf(v);
    bool ok = (a > 1e-6f && a < 1e6f) || v == 0.f;
    unsigned long long m = __ballot(ok);
    return __popcll(m) >= 48;
}
__device__ __forceinline__ bool sniff_i64(const int* __restrict__ eiw) {
    int lane = threadIdx.x & 63;
    unsigned long long m = __ballot(eiw[2 * lane + 1] != 0);
    return __popcll(m) <= 4;
}

__device__ __forceinline__ void edge_sd(const int* ei, int i, bool i64, int& s, int& d) {
    if (i < EE) {
        if (i64) { s = ei[2 * i]; d = ei[2 * (EE + i)]; }
        else     { s = ei[i];     d = ei[EE + i]; }
    } else {
        s = d = i - EE;
    }
}
__device__ __forceinline__ int edge_d(const int* ei, int i, bool i64) {
    if (i < EE) return i64 ? ei[2 * (EE + i)] : ei[EE + i];
    return i - EE;
}

// ---------------- L1: degree histogram + rank (atomic-free fill later) + W pre-transpose ----------------
__global__ __launch_bounds__(256) void prep_kernel(const int* __restrict__ ei, int* __restrict__ deg8,
                                                   int* __restrict__ rank,
                                                   const unsigned int* __restrict__ xw,
                                                   const void* W1v, const void* W2v,
                                                   ushort_t* __restrict__ Wt1, ushort_t* __restrict__ Wt2) {
    int b = blockIdx.x;
    if (b < DEGB) {
        bool i64 = sniff_i64(ei);
        int i = b * 256 + threadIdx.x;
        if (i >= ET) return;
        int g = b & 7;                        // blockIdx->XCD round-robin: atomic lines stay in one L2
        int d = edge_d(ei, i, i64);
        rank[i] = atomicAdd(&deg8[(size_t)g * NN + d], 1);
    } else {
        bool f32 = sniff_f32(xw);
        int i = (b - DEGB) * 256 + threadIdx.x;
        if (i < 128 * 128) {                  // W1[k][nc] -> Wt1[nc][k]
            int k = i >> 7, nc = i & 127;
            ushort_t v = f32 ? f2bf(((const float*)W1v)[i]) : ((const ushort_t*)W1v)[i];
            Wt1[nc * 128 + k] = v;
        }
        int j = i - 128 * 128;
        if (j >= 0 && j < 128 * 64) {         // W2[k][nc] -> Wt2[nc][k]
            int k = j >> 6, nc = j & 63;
            ushort_t v = f32 ? f2bf(((const float*)W2v)[j]) : ((const ushort_t*)W2v)[j];
            Wt2[nc * 128 + k] = v;
        }
    }
}

// ---------------- scan: all-publish-then-all-read (no serial lookback chain) ----------------
// All 196 blocks are co-resident (196 < 256 CUs). Each publishes its aggregate with a flag,
// then wave 0 of each block reads ALL predecessors' aggregates in 64-wide rounds. No P-chain.
#define FLG_A (1ull << 62)

__global__ __launch_bounds__(256) void scan_kernel(int* __restrict__ deg8, int* __restrict__ rowptr,
                                                   unsigned long long* __restrict__ state) {
    __shared__ int wsum[4];
    __shared__ int bpref;
    int b = blockIdx.x;
    int t = threadIdx.x;
    int node = b * 256 + t;
    int lane = t & 63, wid = t >> 6;
    int dv[8];
    int v = 0;
    if (node < NN) {
        #pragma unroll
        for (int g = 0; g < 8; ++g) {
            dv[g] = deg8[(size_t)g * NN + node];
            v += dv[g];
        }
    }
    int x = v;
    #pragma unroll
    for (int off = 1; off < 64; off <<= 1) {
        int y = __shfl_up(x, off);
        if (lane >= off) x += y;
    }
    if (lane == 63) wsum[wid] = x;
    __syncthreads();
    if (t < 4) {
        int s = wsum[t];
        #pragma unroll
        for (int off = 1; off < 4; off <<= 1) {
            int y = __shfl_up(s, off);
            if (t >= off) s += y;
        }
        wsum[t] = s;
    }
    __syncthreads();
    int total = wsum[3];                      // block aggregate
    if (t == 0) atomicExch(&state[b], FLG_A | (unsigned long long)(unsigned)total);
    if (t < 64) {                             // wave-parallel prefix: read all predecessors
        int p = 0;
        #pragma unroll
        for (int w = 0; w < (NCH + 63) / 64; ++w) {
            int j = w * 64 + t;
            unsigned long long sv = 0;
            if (j < b) {
                do { sv = atomicAdd(&state[j], 0ull); __builtin_amdgcn_s_sleep(1); } while (!(sv >> 62));
            }
            p += (int)(unsigned)(sv & 0xffffffffull);
        }
        #pragma unroll
        for (int off = 1; off < 64; off <<= 1) p += __shfl_xor(p, off);
        if (t == 0) bpref = p;
    }
    __syncthreads();
    int excl = x - v + ((wid > 0) ? wsum[wid - 1] : 0);
    if (node < NN) {
        int run = bpref + excl;
        rowptr[node] = run;
        #pragma unroll
        for (int g = 0; g < 8; ++g) {         // deg8 becomes per-slice exclusive offsets for fill
            deg8[(size_t)g * NN + node] = run;
            run += dv[g];
        }
    }
    if (b == NCH - 1 && t == 0) rowptr[NN] = bpref + total;
}

// ---------------- MFMA GEMM body (A streamed global->VGPR, B (Wt) L2-resident) ----------------
template <bool AEXT, int NCOL, int NH>
__device__ __forceinline__ void mgemm_body(int bid, const void* Av, const ushort_t* __restrict__ Wt,
                                           const void* a_src, const void* a_dst,
                                           ushort_t* __restrict__ outb, float* __restrict__ asrc,
                                           float* __restrict__ adst, int n, bool f32) {
    constexpr int K = 128;
    constexpr int NCT = NCOL / 16;
    bool af32 = AEXT && f32;                  // internal A (hmid) is always bf16
    int t = threadIdx.x;
    int lane = t & 63, wid = t >> 6;
    int m = lane & 15, quad = lane >> 4;
    int rbase = bid * 64 + wid * 16;
    int row = rbase + m;
    bool rok = row < n;

    bf16x8 af[4];
    if (rok) {
        if (!af32) {
            const ushort_t* ap = (const ushort_t*)Av + (size_t)row * K + quad * 8;
            #pragma unroll
            for (int kk = 0; kk < 4; ++kk) af[kk] = *(const bf16x8*)(ap + kk * 32);
        } else {
            const float* ap = (const float*)Av + (size_t)row * K + quad * 8;
            #pragma unroll
            for (int kk = 0; kk < 4; ++kk) {
                float4 q0 = *(const float4*)(ap + kk * 32);
                float4 q1 = *(const float4*)(ap + kk * 32 + 4);
                bf16x8 v;
                v[0] = (short)f2bf(q0.x); v[1] = (short)f2bf(q0.y);
                v[2] = (short)f2bf(q0.z); v[3] = (short)f2bf(q0.w);
                v[4] = (short)f2bf(q1.x); v[5] = (short)f2bf(q1.y);
                v[6] = (short)f2bf(q1.z); v[7] = (short)f2bf(q1.w);
                af[kk] = v;
            }
        }
    } else {
        #pragma unroll
        for (int kk = 0; kk < 4; ++kk) af[kk] = (bf16x8){0, 0, 0, 0, 0, 0, 0, 0};
    }

    f32x4 acc[NCT];
    #pragma unroll
    for (int c = 0; c < NCT; ++c) acc[c] = (f32x4){0.f, 0.f, 0.f, 0.f};

    const ushort_t* wp = Wt + (size_t)m * K + quad * 8;
    #pragma unroll
    for (int c = 0; c < NCT; ++c) {
        const ushort_t* wc = wp + (size_t)c * 16 * K;
        #pragma unroll
        for (int kk = 0; kk < 4; ++kk) {
            bf16x8 bf = *(const bf16x8*)(wc + kk * 32);
            acc[c] = __builtin_amdgcn_mfma_f32_16x16x32_bf16(af[kk], bf, acc[c], 0, 0, 0);
        }
    }

    int orow0 = rbase + quad * 4;
    #pragma unroll
    for (int c = 0; c < NCT; ++c) {
        #pragma unroll
        for (int r = 0; r < 4; ++r) {
            int orow = orow0 + r;
            if (orow < n) outb[(size_t)orow * NCOL + c * 16 + m] = f2bf(acc[c][r]);
        }
    }

    if (NH == 8) {
        #pragma unroll
        for (int c = 0; c < NCT; ++c) {
            float as = ldf(a_src, c * 16 + m, f32);
            float ad = ldf(a_dst, c * 16 + m, f32);
            float ps[4], pd[4];
            #pragma unroll
            for (int r = 0; r < 4; ++r) { ps[r] = acc[c][r] * as; pd[r] = acc[c][r] * ad; }
            #pragma unroll
            for (int stp = 1; stp < 16; stp <<= 1) {
                #pragma unroll
                for (int r = 0; r < 4; ++r) {
                    ps[r] += __shfl_xor(ps[r], stp);
                    pd[r] += __shfl_xor(pd[r], stp);
                }
            }
            if (m == 0) {
                #pragma unroll
                for (int r = 0; r < 4; ++r) {
                    int orow = orow0 + r;
                    if (orow < n) {
                        asrc[(size_t)orow * 8 + c] = ps[r];
                        adst[(size_t)orow * 8 + c] = pd[r];
                    }
                }
            }
        }
    } else {
        float ps[4] = {0.f, 0.f, 0.f, 0.f}, pd[4] = {0.f, 0.f, 0.f, 0.f};
        #pragma unroll
        for (int c = 0; c < NCT; ++c) {
            float as = ldf(a_src, c * 16 + m, f32);
            float ad = ldf(a_dst, c * 16 + m, f32);
            #pragma unroll
            for (int r = 0; r < 4; ++r) {
                ps[r] = fmaf(acc[c][r], as, ps[r]);
                pd[r] = fmaf(acc[c][r], ad, pd[r]);
            }
        }
        #pragma unroll
        for (int stp = 1; stp < 16; stp <<= 1) {
            #pragma unroll
            for (int r = 0; r < 4; ++r) {
                ps[r] += __shfl_xor(ps[r], stp);
                pd[r] += __shfl_xor(pd[r], stp);
            }
        }
        if (m == 0) {
            #pragma unroll
            for (int r = 0; r < 4; ++r) {
                int orow = orow0 + r;
                if (orow < n) { asrc[orow] = ps[r]; adst[orow] = pd[r]; }
            }
        }
    }
}

// ---------------- L3: layer-1 GEMM + CSR fill, fused by block range (independent work, no waits) ----------------
// gemm blocks need only prep (Wt1); fill blocks need only prep (rank) + scan (deg8 offsets).
// Both satisfied at launch — the two ranges just co-reside, overlapping MFMA with scattered fill.
__global__ __launch_bounds__(256) void gemm1_fill_kernel(const void* xv, const ushort_t* __restrict__ Wt1,
                                                         const void* as1, const void* ad1,
                                                         ushort_t* __restrict__ h1b,
                                                         float* __restrict__ asrc1, float* __restrict__ adst1,
                                                         const int* __restrict__ ei,
                                                         const int* __restrict__ deg8off,
                                                         const int* __restrict__ rank, int* __restrict__ col) {
    if (blockIdx.x < GEMB) {
        bool f32 = sniff_f32((const unsigned int*)xv);
        mgemm_body<true, 128, 8>(blockIdx.x, xv, Wt1, as1, ad1, h1b, asrc1, adst1, NN, f32);
        return;
    }
    int bb = blockIdx.x - GEMB;               // fill range: same geometry as prep's degree range
    bool i64 = sniff_i64(ei);
    int i = bb * 256 + threadIdx.x;
    if (i >= ET) return;
    int g = bb & 7;                           // same blockIdx->g map as the degree pass
    int s, d;
    edge_sd(ei, i, i64, s, d);
    col[deg8off[(size_t)g * NN + d] + rank[i]] = s;
}

__global__ __launch_bounds__(256) void mgemm2_kernel(const void* Av, const ushort_t* __restrict__ Wt,
                                                     const void* a_src, const void* a_dst,
                                                     ushort_t* __restrict__ outb, float* __restrict__ asrc,
                                                     float* __restrict__ adst, const unsigned int* __restrict__ xw) {
    bool f32 = sniff_f32(xw);
    mgemm_body<false, 64, 1>(blockIdx.x, Av, Wt, a_src, a_dst, outb, asrc, adst, NN, f32);
}

// ---------------- layer-1 aggregation: one wave per dst node, two-phase pipelined gather ----------------
__global__ __launch_bounds__(256) void agg1_kernel(const unsigned int* __restrict__ xw,
                                                   const int* __restrict__ rowptr, const int* __restrict__ col,
                                                   const ushort_t* __restrict__ h1b,
                                                   const float* __restrict__ asrc, const float* __restrict__ adst,
                                                   const void* b1, ushort_t* __restrict__ hmidb) {
    __shared__ float wle[4][8 * 72];
    __shared__ int loff[4][64];
    bool f32 = sniff_f32(xw);
    int lane = threadIdx.x & 63, wid = threadIdx.x >> 6;
    int d = blockIdx.x * 4 + wid;
    if (d >= NN) return;                 // per-wave LDS only; no __syncthreads in this kernel
    int start = rowptr[d], end = rowptr[d + 1];
    int hB = lane >> 3;
    const float4* dp = (const float4*)(adst + (size_t)d * 8);
    float4 ad0 = dp[0], ad1 = dp[1];
    const char* hb = (const char*)h1b + lane * 4;
    float acc0 = 0.f, acc1 = 0.f, ssum = 0.f;
    for (int chunk = start; chunk < end; chunk += 64) {
        int cnt = min(64, end - chunk);
        int c = (chunk + lane < end) ? col[chunk + lane] : 0;
        loff[wid][lane] = c << 8;
        if (lane < cnt) {
            const float4* ap = (const float4*)(asrc + (size_t)c * 8);
            float4 s0 = ap[0], s1 = ap[1];
            wle[wid][0 * 72 + lane] = __expf(lrelu(s0.x + ad0.x));
            wle[wid][1 * 72 + lane] = __expf(lrelu(s0.y + ad0.y));
            wle[wid][2 * 72 + lane] = __expf(lrelu(s0.z + ad0.z));
            wle[wid][3 * 72 + lane] = __expf(lrelu(s0.w + ad0.w));
            wle[wid][4 * 72 + lane] = __expf(lrelu(s1.x + ad1.x));
            wle[wid][5 * 72 + lane] = __expf(lrelu(s1.y + ad1.y));
            wle[wid][6 * 72 + lane] = __expf(lrelu(s1.z + ad1.z));
            wle[wid][7 * 72 + lane] = __expf(lrelu(s1.w + ad1.w));
        }
        #pragma unroll 8
        for (int j = 0; j < cnt; ++j) {
            int off = loff[wid][j];
            float ex = wle[wid][hB * 72 + j];
            unsigned int hv = *(const unsigned int*)(hb + off);
            ssum += ex;
            acc0 = fmaf(ex, __uint_as_float(hv << 16), acc0);
            acc1 = fmaf(ex, __uint_as_float(hv & 0xffff0000u), acc1);
        }
    }
    float inv = 1.f / (ssum + 1e-16f);
    float o0 = fmaf(acc0, inv, ldf(b1, lane * 2, f32));
    float o1 = fmaf(acc1, inv, ldf(b1, lane * 2 + 1, f32));
    o0 = (o0 > 0.f) ? o0 : (__expf(o0) - 1.f);   // ELU
    o1 = (o1 > 0.f) ? o1 : (__expf(o1) - 1.f);
    unsigned int pk = ((unsigned int)f2bf(o1) << 16) | (unsigned int)f2bf(o0);
    *(unsigned int*)(hmidb + (size_t)d * 128 + lane * 2) = pk;
}

// ---------------- layer-2 aggregation + log_softmax ----------------
__global__ __launch_bounds__(256) void agg2_kernel(const unsigned int* __restrict__ xw,
                                                   const int* __restrict__ rowptr, const int* __restrict__ col,
                                                   const ushort_t* __restrict__ h2b,
                                                   const float* __restrict__ asrc, const float* __restrict__ adst,
                                                   const void* b2, float* __restrict__ out) {
    __shared__ float wle[4][64];
    __shared__ int loff[4][64];
    bool f32 = sniff_f32(xw);
    int lane = threadIdx.x & 63, wid = threadIdx.x >> 6;
    int d = blockIdx.x * 4 + wid;
    if (d >= NN) return;
    int start = rowptr[d], end = rowptr[d + 1];
    float ad = adst[d];
    const char* hb = (const char*)h2b + lane * 2;
    float acc = 0.f, ssum = 0.f;
    for (int chunk = start; chunk < end; chunk += 64) {
        int cnt = min(64, end - chunk);
        int c = (chunk + lane < end) ? col[chunk + lane] : 0;
        loff[wid][lane] = c << 7;
        if (lane < cnt) wle[wid][lane] = __expf(lrelu(asrc[c] + ad));
        #pragma unroll 8
        for (int j = 0; j < cnt; ++j) {
            int off = loff[wid][j];
            float ex = wle[wid][j];
            float hv = bf2f(*(const ushort_t*)(hb + off));
            ssum += ex;
            acc = fmaf(ex, hv, acc);
        }
    }
    float o = acc / (ssum + 1e-16f) + ldf(b2, lane, f32);
    float mm = o;
    #pragma unroll
    for (int off = 1; off < 64; off <<= 1) mm = fmaxf(mm, __shfl_xor(mm, off));
    float texp = __expf(o - mm);
    float ts = texp;
    #pragma unroll
    for (int off = 1; off < 64; off <<= 1) ts += __shfl_xor(ts, off);
    float ls = o - mm - __logf(ts);
    out[(size_t)d * 64 + lane] = o;
    out[(size_t)NN * 64 + (size_t)d * 64 + lane] = ls;
}

extern "C" void kernel_launch(void* const* d_in, const int* in_sizes, int n_in,
                              void* d_out, int out_size, void* d_ws, size_t ws_size,
                              hipStream_t stream) {
    const void* x   = d_in[0];
    const int*  ei  = (const int*)d_in[1];
    const void* W1  = d_in[2];
    const void* as1 = d_in[3];
    const void* ad1 = d_in[4];
    const void* b1  = d_in[5];
    const void* W2  = d_in[6];
    const void* as2 = d_in[7];
    const void* ad2 = d_in[8];
    const void* b2  = d_in[9];
    float* out = (float*)d_out;

    char* w = (char*)d_ws;
    auto alloc = [&](size_t bytes) {
        void* p = (void*)w;
        w += (bytes + 255) & ~(size_t)255;
        return p;
    };
    int* deg8     = (int*)alloc((size_t)8 * NN * 4 + 4096);   // +state tail (zeroed together)
    unsigned long long* state = (unsigned long long*)((char*)deg8 + (size_t)8 * NN * 4);
    int* rowptr   = (int*)alloc((size_t)(NN + 1) * 4);
    int* rank     = (int*)alloc((size_t)ET * 4);
    int* colx     = (int*)alloc((size_t)ET * 4);
    ushort_t* Wt1 = (ushort_t*)alloc((size_t)128 * 128 * 2);
    ushort_t* Wt2 = (ushort_t*)alloc((size_t)64 * 128 * 2);
    ushort_t* h1b = (ushort_t*)alloc((size_t)NN * 128 * 2);
    float* asrc1  = (float*)alloc((size_t)NN * 8 * 4);
    float* adst1  = (float*)alloc((size_t)NN * 8 * 4);
    ushort_t* hmidb = (ushort_t*)alloc((size_t)NN * 128 * 2);
    ushort_t* h2b = (ushort_t*)alloc((size_t)NN * 64 * 2);
    float* asrc2  = (float*)alloc((size_t)NN * 4);
    float* adst2  = (float*)alloc((size_t)NN * 4);

    hipMemsetAsync(deg8, 0, (size_t)8 * NN * 4 + (size_t)NCH * 8, stream);

    prep_kernel<<<DEGB + WPB, 256, 0, stream>>>(ei, deg8, rank, (const unsigned int*)x, W1, W2, Wt1, Wt2);
    scan_kernel<<<NCH, 256, 0, stream>>>(deg8, rowptr, state);
    gemm1_fill_kernel<<<GEMB + DEGB, 256, 0, stream>>>(x, Wt1, as1, ad1, h1b, asrc1, adst1,
                                                       ei, deg8, rank, colx);
    agg1_kernel<<<(NN + 3) / 4, 256, 0, stream>>>((const unsigned int*)x, rowptr, colx, h1b,
                                                  asrc1, adst1, b1, hmidb);
    mgemm2_kernel<<<GEMB, 256, 0, stream>>>((const void*)hmidb, Wt2, as2, ad2, h2b, asrc2, adst2,
                                            (const unsigned int*)x);
    agg2_kernel<<<(NN + 3) / 4, 256, 0, stream>>>((const unsigned int*)x, rowptr, colx, h2b,
                                                  asrc2, adst2, b2, out);
}

// Round 3
// 252.030 us; speedup vs baseline: 1.1570x; 1.0056x over previous
//
#include <hip/hip_runtime.h>

#define NN 50000
#define EE 800000
#define ET (EE + NN)
#define NCH ((NN + 255) / 256)                       // 196 scan chunks
#define DEGB ((ET + 255) / 256)                      // 3322 degree/fill blocks
#define WPB ((128 * 128 + 128 * 64 + 255) / 256)     // 96 wtprep blocks
#define GEMB ((NN + 63) / 64)                        // 782 gemm blocks

typedef unsigned short ushort_t;
using bf16x8 = __attribute__((ext_vector_type(8))) short;
using f32x4  = __attribute__((ext_vector_type(4))) float;

__device__ __forceinline__ float bf2f(ushort_t u) {
    return __uint_as_float(((unsigned int)u) << 16);
}
__device__ __forceinline__ ushort_t f2bf(float f) {
    unsigned int u = __float_as_uint(f);
    u += 0x7fffu + ((u >> 16) & 1u);
    return (ushort_t)(u >> 16);
}
__device__ __forceinline__ float lrelu(float e) {
    return fmaxf(e, 0.f) + 0.2f * fminf(e, 0.f);
}
__device__ __forceinline__ float ldf(const void* p, int i, bool f32) {
    return f32 ? ((const float*)p)[i] : bf2f(((const ushort_t*)p)[i]);
}

// ---- block-local dtype sniffers (per-wave ballot) ----
__device__ __forceinline__ bool sniff_f32(const unsigned int* __restrict__ xw) {
    int lane = threadIdx.x & 63;
    float v = __uint_as_float(xw[lane]);
    float a = fabsf(v);
    bool ok = (a > 1e-6f && a < 1e6f) || v == 0.f;
    unsigned long long m = __ballot(ok);
    return __popcll(m) >= 48;
}
__device__ __forceinline__ bool sniff_i64(const int* __restrict__ eiw) {
    int lane = threadIdx.x & 63;
    unsigned long long m = __ballot(eiw[2 * lane + 1] != 0);
    return __popcll(m) <= 4;
}

__device__ __forceinline__ void edge_sd(const int* ei, int i, bool i64, int& s, int& d) {
    if (i < EE) {
        if (i64) { s = ei[2 * i]; d = ei[2 * (EE + i)]; }
        else     { s = ei[i];     d = ei[EE + i]; }
    } else {
        s = d = i - EE;
    }
}
__device__ __forceinline__ int edge_d(const int* ei, int i, bool i64) {
    if (i < EE) return i64 ? ei[2 * (EE + i)] : ei[EE + i];
    return i - EE;
}

// ---------------- L1: degree histogram + rank (atomic-free fill later) + W pre-transpose ----------------
__global__ __launch_bounds__(256) void prep_kernel(const int* __restrict__ ei, int* __restrict__ deg8,
                                                   int* __restrict__ rank,
                                                   const unsigned int* __restrict__ xw,
                                                   const void* W1v, const void* W2v,
                                                   ushort_t* __restrict__ Wt1, ushort_t* __restrict__ Wt2) {
    int b = blockIdx.x;
    if (b < DEGB) {
        bool i64 = sniff_i64(ei);
        int i = b * 256 + threadIdx.x;
        if (i >= ET) return;
        int g = b & 7;                        // blockIdx->XCD round-robin: atomic lines stay in one L2
        int d = edge_d(ei, i, i64);
        rank[i] = atomicAdd(&deg8[(size_t)g * NN + d], 1);
    } else {
        bool f32 = sniff_f32(xw);
        int i = (b - DEGB) * 256 + threadIdx.x;
        if (i < 128 * 128) {                  // W1[k][nc] -> Wt1[nc][k]
            int k = i >> 7, nc = i & 127;
            ushort_t v = f32 ? f2bf(((const float*)W1v)[i]) : ((const ushort_t*)W1v)[i];
            Wt1[nc * 128 + k] = v;
        }
        int j = i - 128 * 128;
        if (j >= 0 && j < 128 * 64) {         // W2[k][nc] -> Wt2[nc][k]
            int k = j >> 6, nc = j & 63;
            ushort_t v = f32 ? f2bf(((const float*)W2v)[j]) : ((const ushort_t*)W2v)[j];
            Wt2[nc * 128 + k] = v;
        }
    }
}

// ---------------- scan: all-publish-then-all-read (no serial lookback chain) ----------------
#define FLG_A (1ull << 62)

__global__ __launch_bounds__(256) void scan_kernel(int* __restrict__ deg8, int* __restrict__ rowptr,
                                                   unsigned long long* __restrict__ state) {
    __shared__ int wsum[4];
    __shared__ int bpref;
    int b = blockIdx.x;
    int t = threadIdx.x;
    int node = b * 256 + t;
    int lane = t & 63, wid = t >> 6;
    int dv[8];
    int v = 0;
    if (node < NN) {
        #pragma unroll
        for (int g = 0; g < 8; ++g) {
            dv[g] = deg8[(size_t)g * NN + node];
            v += dv[g];
        }
    }
    int x = v;
    #pragma unroll
    for (int off = 1; off < 64; off <<= 1) {
        int y = __shfl_up(x, off);
        if (lane >= off) x += y;
    }
    if (lane == 63) wsum[wid] = x;
    __syncthreads();
    if (t < 4) {
        int s = wsum[t];
        #pragma unroll
        for (int off = 1; off < 4; off <<= 1) {
            int y = __shfl_up(s, off);
            if (t >= off) s += y;
        }
        wsum[t] = s;
    }
    __syncthreads();
    int total = wsum[3];                      // block aggregate
    if (t == 0) atomicExch(&state[b], FLG_A | (unsigned long long)(unsigned)total);
    if (t < 64) {                             // wave-parallel prefix: read all predecessors
        int p = 0;
        #pragma unroll
        for (int w = 0; w < (NCH + 63) / 64; ++w) {
            int j = w * 64 + t;
            unsigned long long sv = 0;
            if (j < b) {
                do { sv = atomicAdd(&state[j], 0ull); __builtin_amdgcn_s_sleep(1); } while (!(sv >> 62));
            }
            p += (int)(unsigned)(sv & 0xffffffffull);
        }
        #pragma unroll
        for (int off = 1; off < 64; off <<= 1) p += __shfl_xor(p, off);
        if (t == 0) bpref = p;
    }
    __syncthreads();
    int excl = x - v + ((wid > 0) ? wsum[wid - 1] : 0);
    if (node < NN) {
        int run = bpref + excl;
        rowptr[node] = run;
        #pragma unroll
        for (int g = 0; g < 8; ++g) {         // deg8 becomes per-slice exclusive offsets for fill
            deg8[(size_t)g * NN + node] = run;
            run += dv[g];
        }
    }
    if (b == NCH - 1 && t == 0) rowptr[NN] = bpref + total;
}

// ---------------- MFMA GEMM body (A streamed global->VGPR, B (Wt) L2-resident) ----------------
template <bool AEXT, int NCOL, int NH>
__device__ __forceinline__ void mgemm_body(int bid, const void* Av, const ushort_t* __restrict__ Wt,
                                           const void* a_src, const void* a_dst,
                                           ushort_t* __restrict__ outb, float* __restrict__ asrc,
                                           float* __restrict__ adst, int n, bool f32) {
    constexpr int K = 128;
    constexpr int NCT = NCOL / 16;
    bool af32 = AEXT && f32;                  // internal A (hmid) is always bf16
    int t = threadIdx.x;
    int lane = t & 63, wid = t >> 6;
    int m = lane & 15, quad = lane >> 4;
    int rbase = bid * 64 + wid * 16;
    int row = rbase + m;
    bool rok = row < n;

    bf16x8 af[4];
    if (rok) {
        if (!af32) {
            const ushort_t* ap = (const ushort_t*)Av + (size_t)row * K + quad * 8;
            #pragma unroll
            for (int kk = 0; kk < 4; ++kk) af[kk] = *(const bf16x8*)(ap + kk * 32);
        } else {
            const float* ap = (const float*)Av + (size_t)row * K + quad * 8;
            #pragma unroll
            for (int kk = 0; kk < 4; ++kk) {
                float4 q0 = *(const float4*)(ap + kk * 32);
                float4 q1 = *(const float4*)(ap + kk * 32 + 4);
                bf16x8 v;
                v[0] = (short)f2bf(q0.x); v[1] = (short)f2bf(q0.y);
                v[2] = (short)f2bf(q0.z); v[3] = (short)f2bf(q0.w);
                v[4] = (short)f2bf(q1.x); v[5] = (short)f2bf(q1.y);
                v[6] = (short)f2bf(q1.z); v[7] = (short)f2bf(q1.w);
                af[kk] = v;
            }
        }
    } else {
        #pragma unroll
        for (int kk = 0; kk < 4; ++kk) af[kk] = (bf16x8){0, 0, 0, 0, 0, 0, 0, 0};
    }

    f32x4 acc[NCT];
    #pragma unroll
    for (int c = 0; c < NCT; ++c) acc[c] = (f32x4){0.f, 0.f, 0.f, 0.f};

    const ushort_t* wp = Wt + (size_t)m * K + quad * 8;
    #pragma unroll
    for (int c = 0; c < NCT; ++c) {
        const ushort_t* wc = wp + (size_t)c * 16 * K;
        #pragma unroll
        for (int kk = 0; kk < 4; ++kk) {
            bf16x8 bf = *(const bf16x8*)(wc + kk * 32);
            acc[c] = __builtin_amdgcn_mfma_f32_16x16x32_bf16(af[kk], bf, acc[c], 0, 0, 0);
        }
    }

    int orow0 = rbase + quad * 4;
    #pragma unroll
    for (int c = 0; c < NCT; ++c) {
        #pragma unroll
        for (int r = 0; r < 4; ++r) {
            int orow = orow0 + r;
            if (orow < n) outb[(size_t)orow * NCOL + c * 16 + m] = f2bf(acc[c][r]);
        }
    }

    if (NH == 8) {
        #pragma unroll
        for (int c = 0; c < NCT; ++c) {
            float as = ldf(a_src, c * 16 + m, f32);
            float ad = ldf(a_dst, c * 16 + m, f32);
            float ps[4], pd[4];
            #pragma unroll
            for (int r = 0; r < 4; ++r) { ps[r] = acc[c][r] * as; pd[r] = acc[c][r] * ad; }
            #pragma unroll
            for (int stp = 1; stp < 16; stp <<= 1) {
                #pragma unroll
                for (int r = 0; r < 4; ++r) {
                    ps[r] += __shfl_xor(ps[r], stp);
                    pd[r] += __shfl_xor(pd[r], stp);
                }
            }
            if (m == 0) {
                #pragma unroll
                for (int r = 0; r < 4; ++r) {
                    int orow = orow0 + r;
                    if (orow < n) {
                        asrc[(size_t)orow * 8 + c] = ps[r];
                        adst[(size_t)orow * 8 + c] = pd[r];
                    }
                }
            }
        }
    } else {
        float ps[4] = {0.f, 0.f, 0.f, 0.f}, pd[4] = {0.f, 0.f, 0.f, 0.f};
        #pragma unroll
        for (int c = 0; c < NCT; ++c) {
            float as = ldf(a_src, c * 16 + m, f32);
            float ad = ldf(a_dst, c * 16 + m, f32);
            #pragma unroll
            for (int r = 0; r < 4; ++r) {
                ps[r] = fmaf(acc[c][r], as, ps[r]);
                pd[r] = fmaf(acc[c][r], ad, pd[r]);
            }
        }
        #pragma unroll
        for (int stp = 1; stp < 16; stp <<= 1) {
            #pragma unroll
            for (int r = 0; r < 4; ++r) {
                ps[r] += __shfl_xor(ps[r], stp);
                pd[r] += __shfl_xor(pd[r], stp);
            }
        }
        if (m == 0) {
            #pragma unroll
            for (int r = 0; r < 4; ++r) {
                int orow = orow0 + r;
                if (orow < n) { asrc[orow] = ps[r]; adst[orow] = pd[r]; }
            }
        }
    }
}

// ---------------- L3: layer-1 GEMM + CSR fill, fused by block range ----------------
__global__ __launch_bounds__(256) void gemm1_fill_kernel(const void* xv, const ushort_t* __restrict__ Wt1,
                                                         const void* as1, const void* ad1,
                                                         ushort_t* __restrict__ h1b,
                                                         float* __restrict__ asrc1, float* __restrict__ adst1,
                                                         const int* __restrict__ ei,
                                                         const int* __restrict__ deg8off,
                                                         const int* __restrict__ rank, int* __restrict__ col) {
    if (blockIdx.x < GEMB) {
        bool f32 = sniff_f32((const unsigned int*)xv);
        mgemm_body<true, 128, 8>(blockIdx.x, xv, Wt1, as1, ad1, h1b, asrc1, adst1, NN, f32);
        return;
    }
    int bb = blockIdx.x - GEMB;               // fill range: same geometry as prep's degree range
    bool i64 = sniff_i64(ei);
    int i = bb * 256 + threadIdx.x;
    if (i >= ET) return;
    int g = bb & 7;                           // same blockIdx->g map as the degree pass
    int s, d;
    edge_sd(ei, i, i64, s, d);
    col[deg8off[(size_t)g * NN + d] + rank[i]] = s;
}

__global__ __launch_bounds__(256) void mgemm2_kernel(const void* Av, const ushort_t* __restrict__ Wt,
                                                     const void* a_src, const void* a_dst,
                                                     ushort_t* __restrict__ outb, float* __restrict__ asrc,
                                                     float* __restrict__ adst, const unsigned int* __restrict__ xw) {
    bool f32 = sniff_f32(xw);
    mgemm_body<false, 64, 1>(blockIdx.x, Av, Wt, a_src, a_dst, outb, asrc, adst, NN, f32);
}

// ---------------- layer-1 aggregation: wide-gather (4 edges x 1KB per VMEM instr) ----------------
// lane = sub (16 dim-groups of 8 dims) x eg (4 edge-groups). Per iteration each lane dwordx4-loads
// 16B of its edge's h1b row -> wave moves 1KB/instr instead of 256B. Tail edges get wle=0 so they
// contribute exactly 0 to both sums. Cross-edge-group combine: shfl_xor(16,32).
__global__ __launch_bounds__(256) void agg1_kernel(const unsigned int* __restrict__ xw,
                                                   const int* __restrict__ rowptr, const int* __restrict__ col,
                                                   const ushort_t* __restrict__ h1b,
                                                   const float* __restrict__ asrc, const float* __restrict__ adst,
                                                   const void* b1, ushort_t* __restrict__ hmidb) {
    __shared__ float wle[4][8 * 72];
    __shared__ int loff[4][64];
    bool f32 = sniff_f32(xw);
    int lane = threadIdx.x & 63, wid = threadIdx.x >> 6;
    int d = blockIdx.x * 4 + wid;
    if (d >= NN) return;                 // per-wave LDS only; no __syncthreads in this kernel
    int start = rowptr[d], end = rowptr[d + 1];
    int sub = lane & 15;                 // dim group: dims [8*sub, 8*sub+8)
    int eg  = lane >> 4;                 // edge group 0..3
    int hB  = sub >> 1;                  // head of this dim group (8 dims span one head half)
    const float4* dp = (const float4*)(adst + (size_t)d * 8);
    float4 ad0 = dp[0], ad1 = dp[1];     // wave-uniform broadcast load
    const char* hb = (const char*)h1b + sub * 16;
    float acc[8] = {0.f, 0.f, 0.f, 0.f, 0.f, 0.f, 0.f, 0.f};
    float ssum = 0.f;
    for (int chunk = start; chunk < end; chunk += 64) {
        int cnt = min(64, end - chunk);
        int c = (chunk + lane < end) ? col[chunk + lane] : 0;
        loff[wid][lane] = c << 8;        // byte offset of 256B h1b row (0 for tail: safe)
        if (lane < cnt) {
            const float4* ap = (const float4*)(asrc + (size_t)c * 8);
            float4 s0 = ap[0], s1 = ap[1];
            wle[wid][0 * 72 + lane] = __expf(lrelu(s0.x + ad0.x));
            wle[wid][1 * 72 + lane] = __expf(lrelu(s0.y + ad0.y));
            wle[wid][2 * 72 + lane] = __expf(lrelu(s0.z + ad0.z));
            wle[wid][3 * 72 + lane] = __expf(lrelu(s0.w + ad0.w));
            wle[wid][4 * 72 + lane] = __expf(lrelu(s1.x + ad1.x));
            wle[wid][5 * 72 + lane] = __expf(lrelu(s1.y + ad1.y));
            wle[wid][6 * 72 + lane] = __expf(lrelu(s1.z + ad1.z));
            wle[wid][7 * 72 + lane] = __expf(lrelu(s1.w + ad1.w));
        } else {
            #pragma unroll
            for (int h = 0; h < 8; ++h) wle[wid][h * 72 + lane] = 0.f;
        }
        int niter = (cnt + 3) >> 2;
        #pragma unroll 4
        for (int jj = 0; jj < niter; ++jj) {
            int j = jj * 4 + eg;
            int off = loff[wid][j];
            float ex = wle[wid][hB * 72 + j];
            uint4 hv = *(const uint4*)(hb + off);
            ssum += ex;
            acc[0] = fmaf(ex, __uint_as_float(hv.x << 16), acc[0]);
            acc[1] = fmaf(ex, __uint_as_float(hv.x & 0xffff0000u), acc[1]);
            acc[2] = fmaf(ex, __uint_as_float(hv.y << 16), acc[2]);
            acc[3] = fmaf(ex, __uint_as_float(hv.y & 0xffff0000u), acc[3]);
            acc[4] = fmaf(ex, __uint_as_float(hv.z << 16), acc[4]);
            acc[5] = fmaf(ex, __uint_as_float(hv.z & 0xffff0000u), acc[5]);
            acc[6] = fmaf(ex, __uint_as_float(hv.w << 16), acc[6]);
            acc[7] = fmaf(ex, __uint_as_float(hv.w & 0xffff0000u), acc[7]);
        }
    }
    #pragma unroll
    for (int off = 16; off < 64; off <<= 1) {
        ssum += __shfl_xor(ssum, off);
        #pragma unroll
        for (int k = 0; k < 8; ++k) acc[k] += __shfl_xor(acc[k], off);
    }
    if (eg == 0) {                        // lanes 0..15 write dims [8*sub, 8*sub+8)
        float inv = 1.f / (ssum + 1e-16f);
        uint4 pk;
        unsigned int pw[4];
        #pragma unroll
        for (int k = 0; k < 4; ++k) {
            float o0 = fmaf(acc[2 * k],     inv, ldf(b1, sub * 8 + 2 * k,     f32));
            float o1 = fmaf(acc[2 * k + 1], inv, ldf(b1, sub * 8 + 2 * k + 1, f32));
            o0 = (o0 > 0.f) ? o0 : (__expf(o0) - 1.f);   // ELU
            o1 = (o1 > 0.f) ? o1 : (__expf(o1) - 1.f);
            pw[k] = ((unsigned int)f2bf(o1) << 16) | (unsigned int)f2bf(o0);
        }
        pk.x = pw[0]; pk.y = pw[1]; pk.z = pw[2]; pk.w = pw[3];
        *(uint4*)(hmidb + (size_t)d * 128 + sub * 8) = pk;
    }
}

// ---------------- layer-2 aggregation: wide-gather (8 edges x 1KB per VMEM instr) + log_softmax ----------------
__global__ __launch_bounds__(256) void agg2_kernel(const unsigned int* __restrict__ xw,
                                                   const int* __restrict__ rowptr, const int* __restrict__ col,
                                                   const ushort_t* __restrict__ h2b,
                                                   const float* __restrict__ asrc, const float* __restrict__ adst,
                                                   const void* b2, float* __restrict__ out) {
    __shared__ float wle[4][64];
    __shared__ int loff[4][64];
    bool f32 = sniff_f32(xw);
    int lane = threadIdx.x & 63, wid = threadIdx.x >> 6;
    int d = blockIdx.x * 4 + wid;
    if (d >= NN) return;
    int start = rowptr[d], end = rowptr[d + 1];
    int sub = lane & 7;                  // dim group: classes [8*sub, 8*sub+8)
    int eg  = lane >> 3;                 // edge group 0..7
    float ad = adst[d];
    const char* hb = (const char*)h2b + sub * 16;
    float acc[8] = {0.f, 0.f, 0.f, 0.f, 0.f, 0.f, 0.f, 0.f};
    float ssum = 0.f;
    for (int chunk = start; chunk < end; chunk += 64) {
        int cnt = min(64, end - chunk);
        int c = (chunk + lane < end) ? col[chunk + lane] : 0;
        loff[wid][lane] = c << 7;        // byte offset of 128B h2b row (0 for tail: safe)
        float e = 0.f;
        if (lane < cnt) e = __expf(lrelu(asrc[c] + ad));
        wle[wid][lane] = e;
        int niter = (cnt + 7) >> 3;
        #pragma unroll 2
        for (int jj = 0; jj < niter; ++jj) {
            int j = jj * 8 + eg;
            int off = loff[wid][j];
            float ex = wle[wid][j];
            uint4 hv = *(const uint4*)(hb + off);
            ssum += ex;
            acc[0] = fmaf(ex, __uint_as_float(hv.x << 16), acc[0]);
            acc[1] = fmaf(ex, __uint_as_float(hv.x & 0xffff0000u), acc[1]);
            acc[2] = fmaf(ex, __uint_as_float(hv.y << 16), acc[2]);
            acc[3] = fmaf(ex, __uint_as_float(hv.y & 0xffff0000u), acc[3]);
            acc[4] = fmaf(ex, __uint_as_float(hv.z << 16), acc[4]);
            acc[5] = fmaf(ex, __uint_as_float(hv.z & 0xffff0000u), acc[5]);
            acc[6] = fmaf(ex, __uint_as_float(hv.w << 16), acc[6]);
            acc[7] = fmaf(ex, __uint_as_float(hv.w & 0xffff0000u), acc[7]);
        }
    }
    #pragma unroll
    for (int off = 8; off < 64; off <<= 1) {
        ssum += __shfl_xor(ssum, off);
        #pragma unroll
        for (int k = 0; k < 8; ++k) acc[k] += __shfl_xor(acc[k], off);
    }
    if (eg == 0) {                        // lanes 0..7 hold the full 64-class row, 8 classes each
        float inv = 1.f / (ssum + 1e-16f);
        float o[8];
        #pragma unroll
        for (int k = 0; k < 8; ++k) o[k] = fmaf(acc[k], inv, ldf(b2, sub * 8 + k, f32));
        float mm = o[0];
        #pragma unroll
        for (int k = 1; k < 8; ++k) mm = fmaxf(mm, o[k]);
        #pragma unroll
        for (int off = 1; off < 8; off <<= 1) mm = fmaxf(mm, __shfl_xor(mm, off));
        float ts = 0.f;
        #pragma unroll
        for (int k = 0; k < 8; ++k) ts += __expf(o[k] - mm);
        #pragma unroll
        for (int off = 1; off < 8; off <<= 1) ts += __shfl_xor(ts, off);
        float lg = mm + __logf(ts);
        float4 w0, w1, l0, l1;
        w0.x = o[0]; w0.y = o[1]; w0.z = o[2]; w0.w = o[3];
        w1.x = o[4]; w1.y = o[5]; w1.z = o[6]; w1.w = o[7];
        l0.x = o[0] - lg; l0.y = o[1] - lg; l0.z = o[2] - lg; l0.w = o[3] - lg;
        l1.x = o[4] - lg; l1.y = o[5] - lg; l1.z = o[6] - lg; l1.w = o[7] - lg;
        float* op = out + (size_t)d * 64 + sub * 8;
        *(float4*)op = w0;
        *(float4*)(op + 4) = w1;
        float* lp = out + (size_t)NN * 64 + (size_t)d * 64 + sub * 8;
        *(float4*)lp = l0;
        *(float4*)(lp + 4) = l1;
    }
}

extern "C" void kernel_launch(void* const* d_in, const int* in_sizes, int n_in,
                              void* d_out, int out_size, void* d_ws, size_t ws_size,
                              hipStream_t stream) {
    const void* x   = d_in[0];
    const int*  ei  = (const int*)d_in[1];
    const void* W1  = d_in[2];
    const void* as1 = d_in[3];
    const void* ad1 = d_in[4];
    const void* b1  = d_in[5];
    const void* W2  = d_in[6];
    const void* as2 = d_in[7];
    const void* ad2 = d_in[8];
    const void* b2  = d_in[9];
    float* out = (float*)d_out;

    char* w = (char*)d_ws;
    auto alloc = [&](size_t bytes) {
        void* p = (void*)w;
        w += (bytes + 255) & ~(size_t)255;
        return p;
    };
    int* deg8     = (int*)alloc((size_t)8 * NN * 4 + 4096);   // +state tail (zeroed together)
    unsigned long long* state = (unsigned long long*)((char*)deg8 + (size_t)8 * NN * 4);
    int* rowptr   = (int*)alloc((size_t)(NN + 1) * 4);
    int* rank     = (int*)alloc((size_t)ET * 4);
    int* colx     = (int*)alloc((size_t)ET * 4);
    ushort_t* Wt1 = (ushort_t*)alloc((size_t)128 * 128 * 2);
    ushort_t* Wt2 = (ushort_t*)alloc((size_t)64 * 128 * 2);
    ushort_t* h1b = (ushort_t*)alloc((size_t)NN * 128 * 2);
    float* asrc1  = (float*)alloc((size_t)NN * 8 * 4);
    float* adst1  = (float*)alloc((size_t)NN * 8 * 4);
    ushort_t* hmidb = (ushort_t*)alloc((size_t)NN * 128 * 2);
    ushort_t* h2b = (ushort_t*)alloc((size_t)NN * 64 * 2);
    float* asrc2  = (float*)alloc((size_t)NN * 4);
    float* adst2  = (float*)alloc((size_t)NN * 4);

    hipMemsetAsync(deg8, 0, (size_t)8 * NN * 4 + (size_t)NCH * 8, stream);

    prep_kernel<<<DEGB + WPB, 256, 0, stream>>>(ei, deg8, rank, (const unsigned int*)x, W1, W2, Wt1, Wt2);
    scan_kernel<<<NCH, 256, 0, stream>>>(deg8, rowptr, state);
    gemm1_fill_kernel<<<GEMB + DEGB, 256, 0, stream>>>(x, Wt1, as1, ad1, h1b, asrc1, adst1,
                                                       ei, deg8, rank, colx);
    agg1_kernel<<<(NN + 3) / 4, 256, 0, stream>>>((const unsigned int*)x, rowptr, colx, h1b,
                                                  asrc1, adst1, b1, hmidb);
    mgemm2_kernel<<<GEMB, 256, 0, stream>>>((const void*)hmidb, Wt2, as2, ad2, h2b, asrc2, adst2,
                                            (const unsigned int*)x);
    agg2_kernel<<<(NN + 3) / 4, 256, 0, stream>>>((const unsigned int*)x, rowptr, colx, h2b,
                                                  asrc2, adst2, b2, out);
}